// Round 5
// baseline (1141.688 us; speedup 1.0000x reference)
//
#include <hip/hip_runtime.h>

#define RC       6144       // rows = cols = 6144
#define OCSTRIDE 18432      // IC_N*9 floats per oc slice
#define NB       256        // grid blocks (1 per CU -> co-resident, R4-proven)
#define NT       512        // threads per block (8 waves, 2/SIMD)
#define RPB      24         // rows per block (256*24 = 6144)
#define CPT      12         // cols per thread (512*12 = 6144)
#define UNSCALE  1.52587890625e-05f   // 2^-16 cancels fp8 256x encode scale per iter
#define NBAR     24

typedef float v2f __attribute__((ext_vector_type(2)));

struct Ctrl {
    int   cnt[NBAR];
    float sig_dot;
    float sig_vsq;
    int   pad[6];
};

__device__ __forceinline__ float wave_reduce(float x) {
#pragma unroll
    for (int off = 32; off > 0; off >>= 1) x += __shfl_down(x, off, 64);
    return x;
}

__global__ __launch_bounds__(64) void init_kernel(Ctrl* c) {
    if (threadIdx.x < NBAR) c->cnt[threadIdx.x] = 0;
    if (threadIdx.x == 0) { c->sig_dot = 0.f; c->sig_vsq = 0.f; }
}

// one-shot grid barrier: each counter used exactly once per launch (R4-proven)
__device__ __forceinline__ void grid_barrier(int* cnt) {
    __syncthreads();
    if (threadIdx.x == 0) {
        __hip_atomic_fetch_add(cnt, 1, __ATOMIC_ACQ_REL, __HIP_MEMORY_SCOPE_AGENT);
        while (__hip_atomic_load(cnt, __ATOMIC_ACQUIRE, __HIP_MEMORY_SCOPE_AGENT) < NB)
            __builtin_amdgcn_s_sleep(2);
    }
    __syncthreads();
}

__global__ __launch_bounds__(NT, 2) void fused_kernel(
    const float* __restrict__ conv, const float* __restrict__ u_in,
    float* __restrict__ ub0, float* __restrict__ ub1,
    float* __restrict__ partials, Ctrl* __restrict__ ctrl,
    float* __restrict__ out)
{
    __shared__ float u_lds[RC];          // final phase only (24 KB)
    __shared__ float v_lds[RPB];
    __shared__ float red24[RPB][8];
    __shared__ float redu[RPB][16];
    __shared__ float sred[8];
    __shared__ float sbc;

    const int tid  = threadIdx.x;
    const int lane = tid & 63;
    const int wid  = tid >> 6;
    const int b    = blockIdx.x;
    const int s0   = b * RPB;            // block's row base AND reduce col-slice base

    // ---- one-time: quantize this thread's 8oc x 4ic patch tile into 72 reg dwords
    // wreg[(ocl*3+hh)*3 + d] holds packed fp8 for local row ocl*3+hh, cols 4d..4d+3
    // (global row = 3*(8b+ocl)+hh = s0 + ocl*3+hh; global col = 12*tid + l)
    unsigned wreg[72];
    {
        const float* tb = conv + (size_t)(b * 8) * OCSTRIDE + tid * 36;
#pragma unroll
        for (int ocl = 0; ocl < 8; ++ocl) {
            float f[36];                  // f[m]: ic_l=m/9, hh=(m%9)/3, ww=m%3
            const float4* p4 = reinterpret_cast<const float4*>(tb + (size_t)ocl * OCSTRIDE);
#pragma unroll
            for (int k = 0; k < 9; ++k) {
                const float4 q = p4[k];
                f[4*k] = q.x; f[4*k+1] = q.y; f[4*k+2] = q.z; f[4*k+3] = q.w;
            }
#pragma unroll
            for (int hh = 0; hh < 3; ++hh) {
#pragma unroll
                for (int d = 0; d < 3; ++d) {
                    const int l0 = 4*d, l1 = 4*d+1, l2 = 4*d+2, l3 = 4*d+3;
                    const float a0 = f[(l0/3)*9 + hh*3 + (l0%3)] * 256.f;
                    const float a1 = f[(l1/3)*9 + hh*3 + (l1%3)] * 256.f;
                    const float a2 = f[(l2/3)*9 + hh*3 + (l2%3)] * 256.f;
                    const float a3 = f[(l3/3)*9 + hh*3 + (l3%3)] * 256.f;
                    int w = __builtin_amdgcn_cvt_pk_fp8_f32(a0, a1, 0, false);
                    w     = __builtin_amdgcn_cvt_pk_fp8_f32(a2, a3, w, true);
                    wreg[(ocl*3 + hh)*3 + d] = (unsigned)w;
                }
            }
        }
    }

    // thread's 12 u values (own cols) in registers
    float uv[CPT];
    {
        const float4* s4 = reinterpret_cast<const float4*>(u_in + tid * CPT);
#pragma unroll
        for (int k = 0; k < 3; ++k) {
            const float4 q = s4[k];
            uv[4*k] = q.x; uv[4*k+1] = q.y; uv[4*k+2] = q.z; uv[4*k+3] = q.w;
        }
    }

    int bar = 0;
    float* const ubuf[2] = {ub0, ub1};

#pragma unroll 1
    for (int it = 0; it < 10; ++it) {
        // ---- phase A: v[r] = sum_c Wq[r][c]*u[c], all from registers
#pragma unroll
        for (int r = 0; r < RPB; ++r) {
            float a = 0.f;
#pragma unroll
            for (int d = 0; d < 3; ++d) {
                const unsigned w = wreg[r*3 + d];
                const v2f f01 = __builtin_amdgcn_cvt_pk_f32_fp8(w, false);
                const v2f f23 = __builtin_amdgcn_cvt_pk_f32_fp8(w, true);
                a += f01.x*uv[4*d] + f01.y*uv[4*d+1] + f23.x*uv[4*d+2] + f23.y*uv[4*d+3];
            }
            a = wave_reduce(a);
            if (lane == 0) red24[r][wid] = a;
        }
        __syncthreads();
        if (tid < RPB) {
            float s = 0.f;
#pragma unroll
            for (int w = 0; w < 8; ++w) s += red24[tid][w];
            v_lds[tid] = s * UNSCALE;
        }
        __syncthreads();

        // ---- phase B: this block's contribution to u'[c], thread-local
        float acc[CPT];
#pragma unroll
        for (int e = 0; e < CPT; ++e) acc[e] = 0.f;
#pragma unroll
        for (int r = 0; r < RPB; ++r) {
            const float vv = v_lds[r];                 // LDS broadcast
#pragma unroll
            for (int d = 0; d < 3; ++d) {
                const unsigned w = wreg[r*3 + d];
                const v2f f01 = __builtin_amdgcn_cvt_pk_f32_fp8(w, false);
                const v2f f23 = __builtin_amdgcn_cvt_pk_f32_fp8(w, true);
                acc[4*d]   += f01.x * vv;
                acc[4*d+1] += f01.y * vv;
                acc[4*d+2] += f23.x * vv;
                acc[4*d+3] += f23.y * vv;
            }
        }
        {
            float* pr = partials + (size_t)b * RC + tid * CPT;
            *reinterpret_cast<float4*>(pr)     = make_float4(acc[0], acc[1], acc[2], acc[3]);
            *reinterpret_cast<float4*>(pr + 4) = make_float4(acc[4], acc[5], acc[6], acc[7]);
            *reinterpret_cast<float4*>(pr + 8) = make_float4(acc[8], acc[9], acc[10], acc[11]);
        }
        grid_barrier(&ctrl->cnt[bar++]);

        // ---- cross-block reduce: u'[s0+cl] = sum_rg partials[rg][s0+cl]
        {
            const int cl = tid >> 4;      // 0..31 (24 active)
            const int g  = tid & 15;
            if (cl < RPB) {
                const float* pp = partials + (size_t)g * RC + (s0 + cl);
                float s = 0.f;
#pragma unroll
                for (int k = 0; k < 16; ++k) s += pp[(size_t)(16*k) * RC];
                redu[cl][g] = s;
            }
            __syncthreads();
            if (tid < RPB) {
                float s = 0.f;
#pragma unroll
                for (int k = 0; k < 16; ++k) s += redu[tid][k];
                ubuf[it & 1][s0 + tid] = s;
            }
        }
        grid_barrier(&ctrl->cnt[bar++]);

        // ---- reload own 12 u' values
        {
            const float4* s4 = reinterpret_cast<const float4*>(ubuf[it & 1] + tid * CPT);
#pragma unroll
            for (int k = 0; k < 3; ++k) {
                const float4 q = s4[k];
                uv[4*k] = q.x; uv[4*k+1] = q.y; uv[4*k+2] = q.z; uv[4*k+3] = q.w;
            }
        }
    }

    // ---- final: sigma = 3 * (v/||v||) . (W * u/||u||), fp32 on ORIGINAL conv
    // u_final = ub1 (it=9 wrote ubuf[1]); last v still in v_lds.
    {
        float sq = 0.f;
#pragma unroll
        for (int k = 0; k < 3; ++k) {
            const int i4 = tid + k * NT;
            const float4 q = *reinterpret_cast<const float4*>(ub1 + i4 * 4);
            *reinterpret_cast<float4*>(u_lds + i4 * 4) = q;
            sq += q.x*q.x + q.y*q.y + q.z*q.z + q.w*q.w;
        }
        sq = wave_reduce(sq);
        if (lane == 0) sred[wid] = sq;
        __syncthreads();
        if (tid == 0) {
            float s = 0.f;
#pragma unroll
            for (int w = 0; w < 8; ++w) s += sred[w];
            sbc = rsqrtf(s);
        }
        __syncthreads();
        const float uscale = sbc;

        const int oc0 = b * 8;
        for (int ocl = 0; ocl < 8; ++ocl) {
            const float* base = conv + (size_t)(oc0 + ocl) * OCSTRIDE;
            const float4* p4  = reinterpret_cast<const float4*>(base + tid * 36);
            const float4* q12 = reinterpret_cast<const float4*>(u_lds + 12 * tid);
            float uvf[12];
#pragma unroll
            for (int k = 0; k < 3; ++k) {
                const float4 q = q12[k];
                uvf[4*k] = q.x; uvf[4*k+1] = q.y; uvf[4*k+2] = q.z; uvf[4*k+3] = q.w;
            }
            float acc0 = 0.f, acc1 = 0.f, acc2 = 0.f;
#pragma unroll
            for (int j = 0; j < 9; ++j) {
                const float4 q = p4[j];
                const float el[4] = {q.x, q.y, q.z, q.w};
#pragma unroll
                for (int e = 0; e < 4; ++e) {
                    const int m   = 4*j + e;
                    const int icl = m / 9;
                    const int rem = m - 9*icl;
                    const int hh  = rem / 3;
                    const int ww  = rem - 3*hh;
                    const float pv = el[e] * uvf[icl*3 + ww];
                    if (hh == 0) acc0 += pv;
                    else if (hh == 1) acc1 += pv;
                    else acc2 += pv;
                }
            }
            acc0 = wave_reduce(acc0);
            acc1 = wave_reduce(acc1);
            acc2 = wave_reduce(acc2);
            if (lane == 0) {
                red24[ocl*3 + 0][wid] = acc0;
                red24[ocl*3 + 1][wid] = acc1;
                red24[ocl*3 + 2][wid] = acc2;
            }
        }
        __syncthreads();

        float d = 0.f, vs = 0.f;
        if (tid < RPB) {
            float tv = 0.f;
#pragma unroll
            for (int w = 0; w < 8; ++w) tv += red24[tid][w];
            tv *= uscale;                       // t[r] = W[r,:] . u_hat
            const float vv = v_lds[tid];
            d  = vv * tv;
            vs = vv * vv;
        }
        if (wid == 0) {
            d  = wave_reduce(d);
            vs = wave_reduce(vs);
            if (lane == 0) {
                atomicAdd(&ctrl->sig_dot, d);
                atomicAdd(&ctrl->sig_vsq, vs);
            }
        }
    }
    grid_barrier(&ctrl->cnt[bar++]);

    if (b == 0 && tid == 0) {
        const float d  = __hip_atomic_load(&ctrl->sig_dot, __ATOMIC_RELAXED,
                                           __HIP_MEMORY_SCOPE_AGENT);
        const float vs = __hip_atomic_load(&ctrl->sig_vsq, __ATOMIC_RELAXED,
                                           __HIP_MEMORY_SCOPE_AGENT);
        out[0] = 3.0f * d * rsqrtf(vs);
    }
}

extern "C" void kernel_launch(void* const* d_in, const int* in_sizes, int n_in,
                              void* d_out, int out_size, void* d_ws, size_t ws_size,
                              hipStream_t stream)
{
    const float* conv = (const float*)d_in[0];   // [2048,2048,3,3] fp32
    const float* u_in = (const float*)d_in[1];   // [1,6144] fp32, unit norm
    float* out = (float*)d_out;

    // ws layout (bytes): ub0[24576] | ub1[24576] | Ctrl[128] | partials[6.29MB]
    const size_t OFF_UB1  = (size_t)RC * sizeof(float);
    const size_t OFF_CTRL = 2 * OFF_UB1;
    const size_t OFF_PART = OFF_CTRL + 128;
    const size_t needed   = OFF_PART + (size_t)NB * RC * sizeof(float);
    if (ws_size < needed) return;

    char* ws = (char*)d_ws;
    float* ub0      = (float*)ws;
    float* ub1      = (float*)(ws + OFF_UB1);
    Ctrl*  ctrl     = (Ctrl*)(ws + OFF_CTRL);
    float* partials = (float*)(ws + OFF_PART);

    init_kernel<<<1, 64, 0, stream>>>(ctrl);
    fused_kernel<<<NB, NT, 0, stream>>>(conv, u_in, ub0, ub1, partials, ctrl, out);
}

// Round 6
// 1094.601 us; speedup vs baseline: 1.0430x; 1.0430x over previous
//
#include <hip/hip_runtime.h>

#define RC       6144       // rows = cols = 6144
#define OCSTRIDE 18432      // IC_N*9 floats per oc slice
#define NB       256        // grid blocks (1 per CU -> co-resident)
#define NT       512        // threads per block (8 waves, 2/SIMD)
#define RPB      24         // rows per block
#define CPT      12         // cols per thread (512*12 = 6144)
#define UNSCALE  1.52587890625e-05f   // 2^-16 cancels fp8 256x encode scale per iter
#define NBAR     24

typedef float v2f __attribute__((ext_vector_type(2)));

struct Ctrl {
    int   cnt[NBAR];
    float sig_dot;
    float sig_vsq;
    int   pad[6];
};

__device__ __forceinline__ float wave_reduce(float x) {
#pragma unroll
    for (int off = 32; off > 0; off >>= 1) x += __shfl_down(x, off, 64);
    return x;
}

__global__ __launch_bounds__(64) void init_kernel(Ctrl* c) {
    if (threadIdx.x < NBAR) c->cnt[threadIdx.x] = 0;
    if (threadIdx.x == 0) { c->sig_dot = 0.f; c->sig_vsq = 0.f; }
}

// one-shot grid barrier (R4/R5-proven); each counter used once per launch
__device__ __forceinline__ void grid_barrier(int* cnt) {
    __syncthreads();
    if (threadIdx.x == 0) {
        __hip_atomic_fetch_add(cnt, 1, __ATOMIC_ACQ_REL, __HIP_MEMORY_SCOPE_AGENT);
        while (__hip_atomic_load(cnt, __ATOMIC_ACQUIRE, __HIP_MEMORY_SCOPE_AGENT) < NB)
            __builtin_amdgcn_s_sleep(2);
    }
    __syncthreads();
}

__global__ __launch_bounds__(NT, 2) void fused_kernel(
    const float* __restrict__ conv, const float* __restrict__ u_in,
    float* __restrict__ ub0, float* __restrict__ ub1,
    float* __restrict__ partials, Ctrl* __restrict__ ctrl,
    float* __restrict__ out)
{
    __shared__ float stage[OCSTRIDE];    // 73.7 KB staging (quantize phase only)
    __shared__ float v_lds[RPB];
    __shared__ float red24[RPB][8];
    __shared__ float redu[RPB][16];
    __shared__ float sred[8];

    const int tid  = threadIdx.x;
    const int lane = tid & 63;
    const int wid  = tid >> 6;
    const int b    = blockIdx.x;

    // ---- one-time quantize: 8 oc slices, each LDS-staged with coalesced loads
    // wreg[(ocl*3+hh)*3+d] packs fp8 of cols j=4d..4d+3 (global col 12*tid+j)
    unsigned wreg[72];
    {
        const float4* g4 = reinterpret_cast<const float4*>(conv + (size_t)(b * 8) * OCSTRIDE);
        float4* s4 = reinterpret_cast<float4*>(stage);
        for (int ocl = 0; ocl < 8; ++ocl) {
            __syncthreads();
#pragma unroll
            for (int k = 0; k < 9; ++k)                        // 4608 f4 / 512 thr
                s4[k * NT + tid] = g4[(size_t)ocl * (OCSTRIDE / 4) + k * NT + tid];
            __syncthreads();
            float f[36];                                        // f[(ic_l)*9+hh*3+ww]
            const float4* l4 = reinterpret_cast<const float4*>(stage + tid * 36);
#pragma unroll
            for (int k = 0; k < 9; ++k) {
                const float4 q = l4[k];
                f[4*k] = q.x; f[4*k+1] = q.y; f[4*k+2] = q.z; f[4*k+3] = q.w;
            }
#pragma unroll
            for (int hh = 0; hh < 3; ++hh) {
#pragma unroll
                for (int d = 0; d < 3; ++d) {
                    const int j0 = 4*d, j1 = 4*d+1, j2 = 4*d+2, j3 = 4*d+3;
                    const float a0 = f[(j0/3)*9 + hh*3 + (j0%3)] * 256.f;
                    const float a1 = f[(j1/3)*9 + hh*3 + (j1%3)] * 256.f;
                    const float a2 = f[(j2/3)*9 + hh*3 + (j2%3)] * 256.f;
                    const float a3 = f[(j3/3)*9 + hh*3 + (j3%3)] * 256.f;
                    int w = __builtin_amdgcn_cvt_pk_fp8_f32(a0, a1, 0, false);
                    w     = __builtin_amdgcn_cvt_pk_fp8_f32(a2, a3, w, true);
                    wreg[(ocl*3 + hh)*3 + d] = (unsigned)w;
                }
            }
        }
    }

    // thread's 12 u values in registers
    float uv[CPT];
    {
        const float4* s4 = reinterpret_cast<const float4*>(u_in + tid * CPT);
#pragma unroll
        for (int k = 0; k < 3; ++k) {
            const float4 q = s4[k];
            uv[4*k] = q.x; uv[4*k+1] = q.y; uv[4*k+2] = q.z; uv[4*k+3] = q.w;
        }
    }

    int bar = 0;
    float* const ubuf[2] = {ub0, ub1};

#pragma unroll 1
    for (int it = 0; it < 10; ++it) {
        // ---- phase A: v[r] = Wq[r,:].u, registers only
#pragma unroll
        for (int r = 0; r < RPB; ++r) {
            float a = 0.f;
#pragma unroll
            for (int d = 0; d < 3; ++d) {
                const unsigned w = wreg[r*3 + d];
                const v2f f01 = __builtin_amdgcn_cvt_pk_f32_fp8(w, false);
                const v2f f23 = __builtin_amdgcn_cvt_pk_f32_fp8(w, true);
                a += f01.x*uv[4*d] + f01.y*uv[4*d+1] + f23.x*uv[4*d+2] + f23.y*uv[4*d+3];
            }
            a = wave_reduce(a);
            if (lane == 0) red24[r][wid] = a;
        }
        __syncthreads();
        if (tid < RPB) {
            float s = 0.f;
#pragma unroll
            for (int w = 0; w < 8; ++w) s += red24[tid][w];
            v_lds[tid] = s * UNSCALE;
        }
        __syncthreads();

        // ---- phase B: block's contribution to u'[c], thread-local
        float acc[CPT];
#pragma unroll
        for (int e = 0; e < CPT; ++e) acc[e] = 0.f;
#pragma unroll
        for (int r = 0; r < RPB; ++r) {
            const float vv = v_lds[r];
#pragma unroll
            for (int d = 0; d < 3; ++d) {
                const unsigned w = wreg[r*3 + d];
                const v2f f01 = __builtin_amdgcn_cvt_pk_f32_fp8(w, false);
                const v2f f23 = __builtin_amdgcn_cvt_pk_f32_fp8(w, true);
                acc[4*d]   += f01.x * vv;
                acc[4*d+1] += f01.y * vv;
                acc[4*d+2] += f23.x * vv;
                acc[4*d+3] += f23.y * vv;
            }
        }
        // panel-major partials: panel p = tid/2 (cols 24p..24p+23), row b
        {
            float* pr = partials + (size_t)(tid >> 1) * (NB * RPB)
                                 + b * RPB + (tid & 1) * CPT;
            *reinterpret_cast<float4*>(pr)     = make_float4(acc[0], acc[1], acc[2], acc[3]);
            *reinterpret_cast<float4*>(pr + 4) = make_float4(acc[4], acc[5], acc[6], acc[7]);
            *reinterpret_cast<float4*>(pr + 8) = make_float4(acc[8], acc[9], acc[10], acc[11]);
        }
        grid_barrier(&ctrl->cnt[bar++]);

        // ---- reduce panel b: u'[24b+cl] = sum_g panel[b][g][cl]; reads contiguous
        {
            if (tid < 384) {
                const int cl = tid % RPB;          // t = g*24+cl
                const int g  = tid / RPB;
                const float* pp = partials + (size_t)b * (NB * RPB) + tid;
                float s = 0.f;
#pragma unroll
                for (int k = 0; k < 16; ++k) s += pp[384 * k];
                redu[cl][g] = s;
            }
            __syncthreads();
            if (tid < RPB) {
                float s = 0.f;
#pragma unroll
                for (int k = 0; k < 16; ++k) s += redu[tid][k];
                ubuf[it & 1][b * RPB + tid] = s;
            }
        }
        grid_barrier(&ctrl->cnt[bar++]);

        // ---- reload own 12 u' values (coalesced 24.5 KB per block)
        {
            const float4* s4 = reinterpret_cast<const float4*>(ubuf[it & 1] + tid * CPT);
#pragma unroll
            for (int k = 0; k < 3; ++k) {
                const float4 q = s4[k];
                uv[4*k] = q.x; uv[4*k+1] = q.y; uv[4*k+2] = q.z; uv[4*k+3] = q.w;
            }
        }
    }

    // ---- sigma from register-resident Wq: sigma = 3 * v9^T (Wq/256) u9 / (|v9||u9|)
    {
        // block-local |u9|^2 (block covers all 6144 cols)
        float us = 0.f;
#pragma unroll
        for (int j = 0; j < CPT; ++j) us += uv[j] * uv[j];
        us = wave_reduce(us);
        if (lane == 0) sred[wid] = us;

        // y[r] = Wq[r,:].u9 (raw, = 256*(W u9)[r]) for own 24 rows
#pragma unroll
        for (int r = 0; r < RPB; ++r) {
            float a = 0.f;
#pragma unroll
            for (int d = 0; d < 3; ++d) {
                const unsigned w = wreg[r*3 + d];
                const v2f f01 = __builtin_amdgcn_cvt_pk_f32_fp8(w, false);
                const v2f f23 = __builtin_amdgcn_cvt_pk_f32_fp8(w, true);
                a += f01.x*uv[4*d] + f01.y*uv[4*d+1] + f23.x*uv[4*d+2] + f23.y*uv[4*d+3];
            }
            a = wave_reduce(a);
            if (lane == 0) red24[r][wid] = a;
        }
        __syncthreads();

        float dotb = 0.f, vsb = 0.f;
        if (tid < RPB) {
            float y = 0.f;
#pragma unroll
            for (int w = 0; w < 8; ++w) y += red24[tid][w];
            const float vv = v_lds[tid];       // v9 (own rows), scale W u8 / 256
            dotb = vv * y;
            vsb  = vv * vv;
        }
        if (wid == 0) {
            dotb = wave_reduce(dotb);
            vsb  = wave_reduce(vsb);
            if (lane == 0) {
                atomicAdd(&ctrl->sig_dot, dotb);
                atomicAdd(&ctrl->sig_vsq, vsb);
            }
        }
    }
    grid_barrier(&ctrl->cnt[bar++]);

    if (b == 0 && tid == 0) {
        float usq = 0.f;
#pragma unroll
        for (int w = 0; w < 8; ++w) usq += sred[w];
        const float d  = __hip_atomic_load(&ctrl->sig_dot, __ATOMIC_RELAXED,
                                           __HIP_MEMORY_SCOPE_AGENT);
        const float vs = __hip_atomic_load(&ctrl->sig_vsq, __ATOMIC_RELAXED,
                                           __HIP_MEMORY_SCOPE_AGENT);
        // 3 * dot / (256 * |v9| * |u9|)
        out[0] = 0.01171875f * d * rsqrtf(vs) * rsqrtf(usq);   // 3/256
    }
}

extern "C" void kernel_launch(void* const* d_in, const int* in_sizes, int n_in,
                              void* d_out, int out_size, void* d_ws, size_t ws_size,
                              hipStream_t stream)
{
    const float* conv = (const float*)d_in[0];   // [2048,2048,3,3] fp32
    const float* u_in = (const float*)d_in[1];   // [1,6144] fp32, unit norm
    float* out = (float*)d_out;

    // ws layout (bytes): ub0[24576] | ub1[24576] | Ctrl[128] | partials[6.29MB]
    const size_t OFF_UB1  = (size_t)RC * sizeof(float);
    const size_t OFF_CTRL = 2 * OFF_UB1;
    const size_t OFF_PART = OFF_CTRL + 128;
    const size_t needed   = OFF_PART + (size_t)NB * RC * sizeof(float);
    if (ws_size < needed) return;

    char* ws = (char*)d_ws;
    float* ub0      = (float*)ws;
    float* ub1      = (float*)(ws + OFF_UB1);
    Ctrl*  ctrl     = (Ctrl*)(ws + OFF_CTRL);
    float* partials = (float*)(ws + OFF_PART);

    init_kernel<<<1, 64, 0, stream>>>(ctrl);
    fused_kernel<<<NB, NT, 0, stream>>>(conv, u_in, ub0, ub1, partials, ctrl, out);
}